// Round 9
// baseline (613.755 us; speedup 1.0000x reference)
//
#include <hip/hip_runtime.h>
#include <cstdint>
#include <cstddef>

#define M_DIM 8192
#define N_DIM 4096
#define K_DIM 4096
#define CHUNK_M 4096   // chunked fallback if ws can't hold full converted x

typedef __attribute__((ext_vector_type(8))) short bf16x8;
typedef __attribute__((ext_vector_type(4))) float floatx4;

__device__ __forceinline__ ushort f2bf_rne(float f) {
    union { float f; uint32_t u; } a;
    a.f = f;
    uint32_t u = a.u;
    uint32_t r = (u + 0x7fffu + ((u >> 16) & 1u)) >> 16;
    return (ushort)r;
}

__device__ __forceinline__ uint32_t pk_bf_trunc(float f0, float f1) {
    return __builtin_amdgcn_perm(__float_as_uint(f1), __float_as_uint(f0),
                                 0x07060302u);
}

// ---------------------------------------------------------------------------
// Kernel 1: packed int4 (one signed byte per int32) -> dequant -> bf16 (RNE)
// ---------------------------------------------------------------------------
__global__ void dequant_w_kernel(const int4* __restrict__ pw,
                                 const float* __restrict__ scales,
                                 const float* __restrict__ zps,
                                 uint4* __restrict__ wb, int np4) {
    int p4 = blockIdx.x * blockDim.x + threadIdx.x;
    if (p4 >= np4) return;
    int p = p4 * 4;
    int g = p >> 18;
    float s = scales[g];
    float b = -zps[g] * s;
    int4 v = pw[p4];
    int vv[4] = { v.x, v.y, v.z, v.w };
    ushort o[8];
#pragma unroll
    for (int j = 0; j < 4; ++j) {
        int lo = ((int)((uint32_t)vv[j] << 28)) >> 28;
        int hi = ((int)((uint32_t)vv[j] << 24)) >> 28;
        o[2 * j]     = f2bf_rne(fmaf((float)lo, s, b));
        o[2 * j + 1] = f2bf_rne(fmaf((float)hi, s, b));
    }
    uint4 st;
    st.x = (uint32_t)o[0] | ((uint32_t)o[1] << 16);
    st.y = (uint32_t)o[2] | ((uint32_t)o[3] << 16);
    st.z = (uint32_t)o[4] | ((uint32_t)o[5] << 16);
    st.w = (uint32_t)o[6] | ((uint32_t)o[7] << 16);
    wb[p4] = st;
}

// ---------------------------------------------------------------------------
// Kernel 2: x fp32 -> bf16 (RNE)
// ---------------------------------------------------------------------------
__global__ void convert_x_kernel(const float4* __restrict__ x4,
                                 ushort4* __restrict__ out4, int n4) {
    int i = blockIdx.x * blockDim.x + threadIdx.x;
    if (i >= n4) return;
    float4 v = x4[i];
    ushort4 o;
    o.x = f2bf_rne(v.x);
    o.y = f2bf_rne(v.y);
    o.z = f2bf_rne(v.z);
    o.w = f2bf_rne(v.w);
    out4[i] = o;
}

// ---------------------------------------------------------------------------
// Kernel 3a: 256x256 pipelined bf16 GEMM — A via LDS (ring-4, DMA), B DIRECT
// global->register (no LDS round-trip for B).
// A [M][K] bf16 row-major, B [N][K] bf16 row-major. C = A*B^T + bias.
// 512 threads = 8 waves (2M x 4N), per-wave 128x64 output, acc[8][4].
//
// R9 rationale: R5-R8 plateaued at 57-59% MfmaUtil because per-step LDS
// traffic (96KB frag reads + 32KB DMA writes ~ 1450 cyc) nearly equals the
// MFMA floor (1242 cyc) — any overlap imperfection idles the matrix pipe.
// B frags are consumed from registers anyway; loading them straight from
// global (L2/L3-resident, 33.5MB fully L3-cached) removes 48KB/step of LDS
// traffic: new LDS load ~80KB/step ~ 940 cyc < 1242 -> matrix-bound.
//
// Schedule per step t (tile t = K-rows [t*32, t*32+32)):
//   top: LOAD_B(t+1) -> bfn regs (4x global_load_dwordx4; full-step latency)
//   G1: 4 ds_read afn[0..3] (tile t+1, slot (t+1)&3) + STAGE_A(t+3)
//       -> 8 MFMA (i=0,1)
//   G2: 4 ds_read afn[4..7] -> 8 MFMA (i=2,3)
//   G3: 16 MFMA (i=4..7)
//   end: vmcnt(2) [in-order queue A2(t+2),B4(t+1),A2(t+3) -> certifies
//        A-stage(t+2) in LDS and B(t+1) in regs; A2(t+3) stays in flight],
//        s_barrier.
// Ring-4 A slots: stage(t+3) -> slot of t-1 (readers done in step t-1 < its
// barrier). Reads in step t hit slot (t+1)&3; in-flight writes hit
// (t+2)&3,(t+3)&3 — distinct mod 4. No lgkmcnt in-step (compiler waits at
// next-step first use; reads get a full step to drain).
//
// T2 swizzle on A only (BK=32): slot' = slot ^ ((row>>1)&3), applied as
// inverse-swizzled GLOBAL source (LDS dest linear for global_load_lds) +
// swizzled frag-read column (per-lane constant). B needs no swizzle.
// ---------------------------------------------------------------------------
#define TBM 256
#define TBN 256
#define TBK 32
#define NT  (K_DIM / TBK)        // 128 K-steps
#define SLOT_E 8192              // A-only ring slot: 256 rows x 32 cols

__global__ __launch_bounds__(512, 2)
void gemm_bf16_256(const ushort* __restrict__ A,
                   const ushort* __restrict__ B,
                   const float* __restrict__ bias,
                   float* __restrict__ C) {
    __shared__ ushort lds[4 * SLOT_E];   // 64 KiB (A ring only)

    const int tid  = threadIdx.x;
    const int lane = tid & 63;
    const int wave = tid >> 6;
    const int wm   = wave >> 2;          // 0..1
    const int wn   = wave & 3;           // 0..3

    // T1: XCD-chunked bijective swizzle (nwg % 8 == 0)
    const int nwg = gridDim.x;
    const int cpx = nwg >> 3;
    const int bid = blockIdx.x;
    const int swz = (bid & 7) * cpx + (bid >> 3);
    const int bn  = swz & (N_DIM / TBN - 1);
    const int bm  = swz / (N_DIM / TBN);

    const ushort* Ab = A + (size_t)(bm * TBM) * K_DIM;

    // A staging: thread tid covers LDS offset tid*16B of an 8KB half
    // -> half row tid>>2 (0..127); T2: fetch INVERSE-swizzled global k-chunk
    const int srow = tid >> 2;
    const int scol = (((tid & 3) ^ ((tid >> 3) & 3)) * 8);
    const ushort* gA0 = Ab + (size_t)srow * K_DIM + scol;
    const ushort* gA1 = gA0 + (size_t)128 * K_DIM;
    const int wdst = wave * 512;         // this wave's 1KB within a half

    // A fragment addressing: T2 swizzled slot, constant per lane
    const int frow = lane & 15;
    const int fcolA = (((lane >> 4) ^ ((frow >> 1) & 3)) * 8);
    const int aoff = (wm * 128 + frow) * TBK + fcolA;

    // B direct fragment base: row = bn*256 + wn*64 + (j*16) + frow,
    // col = k0 + (lane>>4)*8 (16B per lane; 4-lane groups span 64B lines)
    const ushort* gBf = B + (size_t)(bn * TBN + wn * 64 + frow) * K_DIM +
                        (lane >> 4) * 8;

    floatx4 acc[8][4] = {};

#define STAGE_A(tt)                                                           \
    {                                                                          \
        const int k0s = ((tt) & (NT - 1)) * TBK;                               \
        ushort* d = lds + ((tt) & 3) * SLOT_E + wdst;                          \
        __builtin_amdgcn_global_load_lds(                                      \
            (const __attribute__((address_space(1))) void*)(gA0 + k0s),        \
            (__attribute__((address_space(3))) void*)d, 16, 0, 0);             \
        __builtin_amdgcn_global_load_lds(                                      \
            (const __attribute__((address_space(1))) void*)(gA1 + k0s),        \
            (__attribute__((address_space(3))) void*)(d + 4096), 16, 0, 0);    \
    }

#define LOAD_B(tt, bfr)                                                       \
    {                                                                          \
        const size_t bk = (size_t)((tt) & (NT - 1)) * TBK;                     \
        _Pragma("unroll")                                                      \
        for (int j = 0; j < 4; ++j)                                            \
            bfr[j] = *(const bf16x8*)(gBf + (size_t)j * 16 * K_DIM + bk);      \
    }

// one K-step: consume afc[8] (LDS, prefetched last step) x bfc[4] (global,
// prefetched last step); prefetch afn/bfn for tile T+1; stage A(T+3).
#define BODY(T, afc, bfc, afn, bfn)                                           \
    {                                                                          \
        LOAD_B((T) + 1, bfn)                                                   \
        const ushort* bnxt = lds + (((T) + 1) & 3) * SLOT_E;                   \
        /* G1: afn[0..3] + stage A(t+3) */                                     \
        _Pragma("unroll")                                                      \
        for (int i = 0; i < 4; ++i)                                            \
            afn[i] = *(const bf16x8*)(bnxt + aoff + i * 512);                  \
        STAGE_A((T) + 3)                                                       \
        __builtin_amdgcn_sched_barrier(0);                                     \
        __builtin_amdgcn_s_setprio(1);                                         \
        _Pragma("unroll")                                                      \
        for (int i = 0; i < 2; ++i)                                            \
            _Pragma("unroll")                                                  \
            for (int j = 0; j < 4; ++j)                                        \
                acc[i][j] = __builtin_amdgcn_mfma_f32_16x16x32_bf16(           \
                    afc[i], bfc[j], acc[i][j], 0, 0, 0);                       \
        __builtin_amdgcn_s_setprio(0);                                         \
        __builtin_amdgcn_sched_barrier(0);                                     \
        /* G2: afn[4..7] */                                                    \
        _Pragma("unroll")                                                      \
        for (int i = 4; i < 8; ++i)                                            \
            afn[i] = *(const bf16x8*)(bnxt + aoff + i * 512);                  \
        __builtin_amdgcn_sched_barrier(0);                                     \
        __builtin_amdgcn_s_setprio(1);                                         \
        _Pragma("unroll")                                                      \
        for (int i = 2; i < 4; ++i)                                            \
            _Pragma("unroll")                                                  \
            for (int j = 0; j < 4; ++j)                                        \
                acc[i][j] = __builtin_amdgcn_mfma_f32_16x16x32_bf16(           \
                    afc[i], bfc[j], acc[i][j], 0, 0, 0);                       \
        __builtin_amdgcn_s_setprio(0);                                         \
        __builtin_amdgcn_sched_barrier(0);                                     \
        /* G3: remaining 16 MFMA */                                            \
        __builtin_amdgcn_s_setprio(1);                                         \
        _Pragma("unroll")                                                      \
        for (int i = 4; i < 8; ++i)                                            \
            _Pragma("unroll")                                                  \
            for (int j = 0; j < 4; ++j)                                        \
                acc[i][j] = __builtin_amdgcn_mfma_f32_16x16x32_bf16(           \
                    afc[i], bfc[j], acc[i][j], 0, 0, 0);                       \
        __builtin_amdgcn_s_setprio(0);                                         \
        /* certify A-stage(t+2) in LDS + B(t+1) in regs; A2(t+3) flies */      \
        asm volatile("s_waitcnt vmcnt(2)" ::: "memory");                       \
        __builtin_amdgcn_s_barrier();                                          \
        __builtin_amdgcn_sched_barrier(0);                                     \
    }

    // ---- prologue ----
    // vmem issue order: B4(0) first (oldest), then A stages 0,1,2.
    // vmcnt(2) completes B4(0)+A2(0)+A2(1), leaves A2(2) -> matches the
    // steady-state invariant "before step t: only A2(t+2) outstanding".
    bf16x8 af0[8], bf0[4], af1[8], bf1[4];
    LOAD_B(0, bf0)
    STAGE_A(0) STAGE_A(1) STAGE_A(2)
    asm volatile("s_waitcnt vmcnt(2)" ::: "memory");
    __builtin_amdgcn_s_barrier();
    __builtin_amdgcn_sched_barrier(0);

    // initial A fragment set: tile 0 (slot 0; certified landed above)
#pragma unroll
    for (int i = 0; i < 8; ++i)
        af0[i] = *(const bf16x8*)(lds + aoff + i * 512);

    for (int t = 0; t < NT; t += 2) {
        BODY(t,     af0, bf0, af1, bf1)
        BODY(t + 1, af1, bf1, af0, bf0)
    }
#undef BODY
#undef LOAD_B
#undef STAGE_A

    // epilogue: C = acc + bias
    const int crow0 = bm * TBM + wm * 128;
    const int ccol0 = bn * TBN + wn * 64;
    const int rl = lane >> 4;
    const int cl = lane & 15;
#pragma unroll
    for (int j = 0; j < 4; ++j) {
        const int col = ccol0 + j * 16 + cl;
        const float bv = bias[col];
#pragma unroll
        for (int i = 0; i < 8; ++i) {
            const int row = crow0 + i * 16 + rl * 4;
            float* cp = C + (size_t)row * N_DIM + col;
#pragma unroll
            for (int r = 0; r < 4; ++r)
                cp[(size_t)r * N_DIM] = acc[i][j][r] + bv;
        }
    }
}

// ---------------------------------------------------------------------------
// Kernel 3b (fallback if ws too small): fused fp32-A GEMM, 128x128 tile.
// ---------------------------------------------------------------------------
#define BM 128
#define BN 128
#define BK 32

__global__ void gemm_fused_kernel(const float* __restrict__ X,
                                  const ushort* __restrict__ B,
                                  const float* __restrict__ bias,
                                  float* __restrict__ C) {
    __shared__ ushort As[BM * BK];
    __shared__ ushort Bs[BN * BK];

    const int tid  = threadIdx.x;
    const int lane = tid & 63;
    const int wave = tid >> 6;
    const int wm   = wave >> 1;
    const int wn   = wave & 1;
    const int bm   = blockIdx.y;
    const int bn   = blockIdx.x;

    const int ar = tid >> 2;
    const int ac = (tid & 3) * 8;
    const float* xp0 = X + (size_t)(bm * BM + ar) * K_DIM + ac;
    const float* xp1 = xp0 + (size_t)64 * K_DIM;
    ushort* as0 = As + ar * BK + ac;
    ushort* as1 = as0 + 64 * BK;

    const int scol = (lane & 3) * 8;
    const ushort* Bb = B + (size_t)(bn * BN) * K_DIM;

    floatx4 acc[4][4] = {};

    for (int k0 = 0; k0 < K_DIM; k0 += BK) {
        float4 a0 = *(const float4*)(xp0 + k0);
        float4 a1 = *(const float4*)(xp0 + k0 + 4);
        float4 b0 = *(const float4*)(xp1 + k0);
        float4 b1 = *(const float4*)(xp1 + k0 + 4);
#pragma unroll
        for (int q = 0; q < 2; ++q) {
            const int chunk = wave * 2 + q;
            const int r = chunk * 16 + (lane >> 2);
            const ushort* gb = Bb + (size_t)r * K_DIM + k0 + scol;
            __builtin_amdgcn_global_load_lds(
                (const __attribute__((address_space(1))) void*)gb,
                (__attribute__((address_space(3))) void*)(Bs + chunk * 512),
                16, 0, 0);
        }
        uint4 w0, w1;
        w0.x = pk_bf_trunc(a0.x, a0.y);
        w0.y = pk_bf_trunc(a0.z, a0.w);
        w0.z = pk_bf_trunc(a1.x, a1.y);
        w0.w = pk_bf_trunc(a1.z, a1.w);
        w1.x = pk_bf_trunc(b0.x, b0.y);
        w1.y = pk_bf_trunc(b0.z, b0.w);
        w1.z = pk_bf_trunc(b1.x, b1.y);
        w1.w = pk_bf_trunc(b1.z, b1.w);
        *(uint4*)as0 = w0;
        *(uint4*)as1 = w1;

        __syncthreads();

        bf16x8 af[4], bfr[4];
        const int frow = lane & 15;
        const int fcol = (lane >> 4) * 8;
#pragma unroll
        for (int i = 0; i < 4; ++i) {
            af[i]  = *(const bf16x8*)(As + (wm * 64 + i * 16 + frow) * BK + fcol);
            bfr[i] = *(const bf16x8*)(Bs + (wn * 64 + i * 16 + frow) * BK + fcol);
        }
#pragma unroll
        for (int i = 0; i < 4; ++i)
#pragma unroll
            for (int j = 0; j < 4; ++j)
                acc[i][j] = __builtin_amdgcn_mfma_f32_16x16x32_bf16(
                    af[i], bfr[j], acc[i][j], 0, 0, 0);
        __syncthreads();
    }

    const int crow0 = bm * BM + wm * 64;
    const int ccol0 = bn * BN + wn * 64;
    const int rl = lane >> 4;
    const int cl = lane & 15;
#pragma unroll
    for (int j = 0; j < 4; ++j) {
        const int col = ccol0 + j * 16 + cl;
        const float bv = bias[col];
#pragma unroll
        for (int i = 0; i < 4; ++i) {
            const int row = crow0 + i * 16 + rl * 4;
            float* cp = C + (size_t)row * N_DIM + col;
#pragma unroll
            for (int r = 0; r < 4; ++r)
                cp[(size_t)r * N_DIM] = acc[i][j][r] + bv;
        }
    }
}

// ---------------------------------------------------------------------------
extern "C" void kernel_launch(void* const* d_in, const int* in_sizes, int n_in,
                              void* d_out, int out_size, void* d_ws, size_t ws_size,
                              hipStream_t stream) {
    const float* x      = (const float*)d_in[0];
    const int*   pw     = (const int*)d_in[1];
    const float* scales = (const float*)d_in[2];
    const float* zps    = (const float*)d_in[3];
    const float* bias   = (const float*)d_in[4];
    float* out = (float*)d_out;

    ushort* wb = (ushort*)d_ws;                        // 33.5 MB

    {
        int np4 = (N_DIM * K_DIM / 2) / 4;
        dequant_w_kernel<<<np4 / 256, 256, 0, stream>>>(
            (const int4*)pw, scales, zps, (uint4*)wb, np4);
    }

    const size_t need_full  = ((size_t)N_DIM * K_DIM + (size_t)M_DIM * K_DIM) * 2;
    const size_t need_chunk = ((size_t)N_DIM * K_DIM + (size_t)CHUNK_M * K_DIM) * 2;

    if (ws_size >= need_full) {
        // full path: convert all of x once, single GEMM over M=8192
        ushort* xb = wb + (size_t)N_DIM * K_DIM;       // 67.1 MB
        int n4 = (M_DIM * K_DIM) / 4;
        convert_x_kernel<<<n4 / 256, 256, 0, stream>>>(
            (const float4*)x, (ushort4*)xb, n4);
        int nblk = (M_DIM / TBM) * (N_DIM / TBN);      // 32*16 = 512
        gemm_bf16_256<<<nblk, 512, 0, stream>>>(xb, wb, bias, out);
    } else if (ws_size >= need_chunk) {
        // chunked path
        ushort* xb = wb + (size_t)N_DIM * K_DIM;
        for (int c = 0; c < M_DIM / CHUNK_M; ++c) {
            const float* xc = x + (size_t)c * CHUNK_M * K_DIM;
            float* oc = out + (size_t)c * CHUNK_M * N_DIM;
            int n4 = (CHUNK_M * K_DIM) / 4;
            convert_x_kernel<<<n4 / 256, 256, 0, stream>>>(
                (const float4*)xc, (ushort4*)xb, n4);
            int nblk = (CHUNK_M / TBM) * (N_DIM / TBN);
            gemm_bf16_256<<<nblk, 512, 0, stream>>>(xb, wb, bias, oc);
        }
    } else {
        // fallback: fused conversion
        dim3 grid(N_DIM / BN, M_DIM / BM);
        gemm_fused_kernel<<<grid, 256, 0, stream>>>(x, wb, bias, out);
    }
}

// Round 10
// 475.853 us; speedup vs baseline: 1.2898x; 1.2898x over previous
//
#include <hip/hip_runtime.h>
#include <cstdint>
#include <cstddef>

#define M_DIM 8192
#define N_DIM 4096
#define K_DIM 4096
#define CHUNK_M 4096   // chunked fallback if ws can't hold full converted x

typedef __attribute__((ext_vector_type(8))) short bf16x8;
typedef __attribute__((ext_vector_type(4))) float floatx4;

__device__ __forceinline__ ushort f2bf_rne(float f) {
    union { float f; uint32_t u; } a;
    a.f = f;
    uint32_t u = a.u;
    uint32_t r = (u + 0x7fffu + ((u >> 16) & 1u)) >> 16;
    return (ushort)r;
}

__device__ __forceinline__ uint32_t pk_bf_trunc(float f0, float f1) {
    return __builtin_amdgcn_perm(__float_as_uint(f1), __float_as_uint(f0),
                                 0x07060302u);
}

// ---------------------------------------------------------------------------
// Kernel 1: packed int4 (one signed byte per int32) -> dequant -> bf16 (RNE)
// ---------------------------------------------------------------------------
__global__ void dequant_w_kernel(const int4* __restrict__ pw,
                                 const float* __restrict__ scales,
                                 const float* __restrict__ zps,
                                 uint4* __restrict__ wb, int np4) {
    int p4 = blockIdx.x * blockDim.x + threadIdx.x;
    if (p4 >= np4) return;
    int p = p4 * 4;
    int g = p >> 18;
    float s = scales[g];
    float b = -zps[g] * s;
    int4 v = pw[p4];
    int vv[4] = { v.x, v.y, v.z, v.w };
    ushort o[8];
#pragma unroll
    for (int j = 0; j < 4; ++j) {
        int lo = ((int)((uint32_t)vv[j] << 28)) >> 28;
        int hi = ((int)((uint32_t)vv[j] << 24)) >> 28;
        o[2 * j]     = f2bf_rne(fmaf((float)lo, s, b));
        o[2 * j + 1] = f2bf_rne(fmaf((float)hi, s, b));
    }
    uint4 st;
    st.x = (uint32_t)o[0] | ((uint32_t)o[1] << 16);
    st.y = (uint32_t)o[2] | ((uint32_t)o[3] << 16);
    st.z = (uint32_t)o[4] | ((uint32_t)o[5] << 16);
    st.w = (uint32_t)o[6] | ((uint32_t)o[7] << 16);
    wb[p4] = st;
}

// ---------------------------------------------------------------------------
// Kernel 2: x fp32 -> bf16 (RNE), 8 floats/thread (16B store coalescing)
// ---------------------------------------------------------------------------
__global__ void convert_x_kernel(const float4* __restrict__ x4,
                                 uint4* __restrict__ out4, int n8) {
    int i = blockIdx.x * blockDim.x + threadIdx.x;
    if (i >= n8) return;
    float4 a = x4[2 * i];
    float4 b = x4[2 * i + 1];
    uint4 o;
    o.x = (uint32_t)f2bf_rne(a.x) | ((uint32_t)f2bf_rne(a.y) << 16);
    o.y = (uint32_t)f2bf_rne(a.z) | ((uint32_t)f2bf_rne(a.w) << 16);
    o.z = (uint32_t)f2bf_rne(b.x) | ((uint32_t)f2bf_rne(b.y) << 16);
    o.w = (uint32_t)f2bf_rne(b.z) | ((uint32_t)f2bf_rne(b.w) << 16);
    out4[i] = o;
}

// ---------------------------------------------------------------------------
// Kernel 3a: 256x256 pipelined bf16 GEMM (R8: flat counted-vmcnt schedule +
// full next-tile register prefetch -> zero in-step LDS waits). BEST: 227us.
// A [M][K] bf16 row-major, B [N][K] bf16 row-major. C = A*B^T + bias.
// 512 threads = 8 waves (2M x 4N), per-wave 128x64 output, acc[8][4].
//
// Step t computes ALL 32 MFMA of tile t from regs loaded in step t-1, and
// issues the 12 ds_reads for tile t+1's frags (3 groups of 4, interleaved
// between MFMA clusters). NO lgkmcnt in-step: reads have a full step
// (~2000 cyc) to drain under the MFMAs; compiler's auto-wait at next-step
// first-use finds them retired. Only syncs per step: vmcnt(4) + s_barrier.
//
// Invariants (ring of 4 slots):
//   stage(t+3) issued in step t into slot (t+3)&3 = slot of t-1, whose
//   readers (frag reads for t-1, issued step t-2) completed before their
//   use in step t-1 < beta(t-1).  Reads in step t target slot (t+1)&3;
//   writes in flight target (t+2)&3, (t+3)&3 - distinct mod 4.
//   vmcnt(4) at end of step t certifies stage(t+2) landed (4 loads of
//   t+3 may fly); BODY(t+1)'s reads of tile t+2 are therefore safe.
//
// T2 swizzle (BK=32, rows = 4 x 16B slots): slot' = slot ^ ((row>>1)&3),
// applied as inverse-swizzled GLOBAL source (LDS dest stays linear for
// global_load_lds) + swizzled fragment-read address (per-lane constant).
//
// NOTE (R7/R9 negative results): replacing either operand's DMA+LDS path
// with per-lane VMEM (fused fp32 A, direct-reg B) regresses ~2x — gather
// transaction-splitting + same-step vmcnt latency lands on the critical
// path. Keep both operands on global_load_lds.
// ---------------------------------------------------------------------------
#define TBM 256
#define TBN 256
#define TBK 32
#define NT  (K_DIM / TBK)        // 128 K-steps
#define A_E 8192                 // elements of A per slot (256*32)
#define SLOT_E 16384             // elements per ring slot (A + B)

__global__ __launch_bounds__(512, 2)
void gemm_bf16_256(const ushort* __restrict__ A,
                   const ushort* __restrict__ B,
                   const float* __restrict__ bias,
                   float* __restrict__ C) {
    __shared__ ushort lds[4 * SLOT_E];   // 128 KiB -> 1 block/CU, 8 waves

    const int tid  = threadIdx.x;
    const int lane = tid & 63;
    const int wave = tid >> 6;
    const int wm   = wave >> 2;          // 0..1
    const int wn   = wave & 3;           // 0..3

    // T1: XCD-chunked bijective swizzle (nwg % 8 == 0)
    const int nwg = gridDim.x;
    const int cpx = nwg >> 3;
    const int bid = blockIdx.x;
    const int swz = (bid & 7) * cpx + (bid >> 3);
    const int bn  = swz & (N_DIM / TBN - 1);
    const int bm  = swz / (N_DIM / TBN);

    const ushort* Ab = A + (size_t)(bm * TBM) * K_DIM;
    const ushort* Bb = B + (size_t)(bn * TBN) * K_DIM;

    // staging: thread tid covers LDS offset tid*16B of an 8KB part
    // -> part row tid>>2 (0..127); T2: fetch INVERSE-swizzled global k-chunk
    const int srow = tid >> 2;
    const int scol = (((tid & 3) ^ ((tid >> 3) & 3)) * 8);
    const ushort* gA0 = Ab + (size_t)srow * K_DIM + scol;
    const ushort* gA1 = gA0 + (size_t)128 * K_DIM;
    const ushort* gB0 = Bb + (size_t)srow * K_DIM + scol;
    const ushort* gB1 = gB0 + (size_t)128 * K_DIM;
    const int wdst = wave * 512;         // this wave's 1KB within a part

    // MFMA fragment addressing: T2 swizzled slot, constant per lane
    const int frow = lane & 15;
    const int fcol = (((lane >> 4) ^ ((frow >> 1) & 3)) * 8);
    const int aoff = (wm * 128 + frow) * TBK + fcol;          // within A region
    const int boff = A_E + (wn * 64 + frow) * TBK + fcol;     // within B region

    floatx4 acc[8][4] = {};

#define STAGE_A(tt)                                                           \
    {                                                                          \
        const int k0s = ((tt) & (NT - 1)) * TBK;                               \
        ushort* d = lds + ((tt) & 3) * SLOT_E + wdst;                          \
        __builtin_amdgcn_global_load_lds(                                      \
            (const __attribute__((address_space(1))) void*)(gA0 + k0s),        \
            (__attribute__((address_space(3))) void*)d, 16, 0, 0);             \
        __builtin_amdgcn_global_load_lds(                                      \
            (const __attribute__((address_space(1))) void*)(gA1 + k0s),        \
            (__attribute__((address_space(3))) void*)(d + 4096), 16, 0, 0);    \
    }
#define STAGE_B(tt)                                                           \
    {                                                                          \
        const int k0s = ((tt) & (NT - 1)) * TBK;                               \
        ushort* d = lds + ((tt) & 3) * SLOT_E + A_E + wdst;                    \
        __builtin_amdgcn_global_load_lds(                                      \
            (const __attribute__((address_space(1))) void*)(gB0 + k0s),        \
            (__attribute__((address_space(3))) void*)d, 16, 0, 0);             \
        __builtin_amdgcn_global_load_lds(                                      \
            (const __attribute__((address_space(1))) void*)(gB1 + k0s),        \
            (__attribute__((address_space(3))) void*)(d + 4096), 16, 0, 0);    \
    }

// one K-step: consume tile T's frags (afc[8], bfc[4], loaded last step);
// prefetch tile T+1's frags into afn[8]/bfn[4]; stage tile T+3.
#define BODY(T, afc, bfc, afn, bfn)                                           \
    {                                                                          \
        const ushort* bnxt = lds + (((T) + 1) & 3) * SLOT_E;                   \
        /* G1: afn[0..3] + stage A(t+3) */                                     \
        _Pragma("unroll")                                                      \
        for (int i = 0; i < 4; ++i)                                            \
            afn[i] = *(const bf16x8*)(bnxt + aoff + i * 512);                  \
        STAGE_A((T) + 3)                                                       \
        __builtin_amdgcn_sched_barrier(0);                                     \
        __builtin_amdgcn_s_setprio(1);                                         \
        _Pragma("unroll")                                                      \
        for (int i = 0; i < 2; ++i)                                            \
            _Pragma("unroll")                                                  \
            for (int j = 0; j < 4; ++j)                                        \
                acc[i][j] = __builtin_amdgcn_mfma_f32_16x16x32_bf16(           \
                    afc[i], bfc[j], acc[i][j], 0, 0, 0);                       \
        __builtin_amdgcn_s_setprio(0);                                         \
        __builtin_amdgcn_sched_barrier(0);                                     \
        /* G2: bfn[0..3] + stage B(t+3) */                                     \
        _Pragma("unroll")                                                      \
        for (int j = 0; j < 4; ++j)                                            \
            bfn[j] = *(const bf16x8*)(bnxt + boff + j * 512);                  \
        STAGE_B((T) + 3)                                                       \
        __builtin_amdgcn_sched_barrier(0);                                     \
        __builtin_amdgcn_s_setprio(1);                                         \
        _Pragma("unroll")                                                      \
        for (int i = 2; i < 4; ++i)                                            \
            _Pragma("unroll")                                                  \
            for (int j = 0; j < 4; ++j)                                        \
                acc[i][j] = __builtin_amdgcn_mfma_f32_16x16x32_bf16(           \
                    afc[i], bfc[j], acc[i][j], 0, 0, 0);                       \
        __builtin_amdgcn_s_setprio(0);                                         \
        __builtin_amdgcn_sched_barrier(0);                                     \
        /* G3: afn[4..7] */                                                    \
        _Pragma("unroll")                                                      \
        for (int i = 4; i < 8; ++i)                                            \
            afn[i] = *(const bf16x8*)(bnxt + aoff + i * 512);                  \
        __builtin_amdgcn_sched_barrier(0);                                     \
        __builtin_amdgcn_s_setprio(1);                                         \
        _Pragma("unroll")                                                      \
        for (int i = 4; i < 8; ++i)                                            \
            _Pragma("unroll")                                                  \
            for (int j = 0; j < 4; ++j)                                        \
                acc[i][j] = __builtin_amdgcn_mfma_f32_16x16x32_bf16(           \
                    afc[i], bfc[j], acc[i][j], 0, 0, 0);                       \
        __builtin_amdgcn_s_setprio(0);                                         \
        /* certify stage(t+2) landed (t+3's 4 loads may fly) */                \
        asm volatile("s_waitcnt vmcnt(4)" ::: "memory");                       \
        __builtin_amdgcn_s_barrier();                                          \
        __builtin_amdgcn_sched_barrier(0);                                     \
    }

    // prologue: tiles 0,1,2 in flight; vmcnt(4) -> tiles 0,1 landed (2 flying)
    STAGE_A(0) STAGE_B(0)
    STAGE_A(1) STAGE_B(1)
    STAGE_A(2) STAGE_B(2)
    asm volatile("s_waitcnt vmcnt(4)" ::: "memory");
    __builtin_amdgcn_s_barrier();
    __builtin_amdgcn_sched_barrier(0);

    // initial fragment set: tile 0 (slot 0). Tile 1 is also certified landed,
    // so BODY(0)'s prefetch of tile 1 is safe.
    bf16x8 af0[8], bf0[4], af1[8], bf1[4];
#pragma unroll
    for (int j = 0; j < 4; ++j)
        bf0[j] = *(const bf16x8*)(lds + boff + j * 512);
#pragma unroll
    for (int i = 0; i < 8; ++i)
        af0[i] = *(const bf16x8*)(lds + aoff + i * 512);

    for (int t = 0; t < NT; t += 2) {
        BODY(t,     af0, bf0, af1, bf1)
        BODY(t + 1, af1, bf1, af0, bf0)
    }
#undef BODY
#undef STAGE_A
#undef STAGE_B

    // epilogue: C = acc + bias
    const int crow0 = bm * TBM + wm * 128;
    const int ccol0 = bn * TBN + wn * 64;
    const int rl = lane >> 4;
    const int cl = lane & 15;
#pragma unroll
    for (int j = 0; j < 4; ++j) {
        const int col = ccol0 + j * 16 + cl;
        const float bv = bias[col];
#pragma unroll
        for (int i = 0; i < 8; ++i) {
            const int row = crow0 + i * 16 + rl * 4;
            float* cp = C + (size_t)row * N_DIM + col;
#pragma unroll
            for (int r = 0; r < 4; ++r)
                cp[(size_t)r * N_DIM] = acc[i][j][r] + bv;
        }
    }
}

// ---------------------------------------------------------------------------
// Kernel 3b (fallback if ws too small): fused fp32-A GEMM, 128x128 tile.
// ---------------------------------------------------------------------------
#define BM 128
#define BN 128
#define BK 32

__global__ void gemm_fused_kernel(const float* __restrict__ X,
                                  const ushort* __restrict__ B,
                                  const float* __restrict__ bias,
                                  float* __restrict__ C) {
    __shared__ ushort As[BM * BK];
    __shared__ ushort Bs[BN * BK];

    const int tid  = threadIdx.x;
    const int lane = tid & 63;
    const int wave = tid >> 6;
    const int wm   = wave >> 1;
    const int wn   = wave & 1;
    const int bm   = blockIdx.y;
    const int bn   = blockIdx.x;

    const int ar = tid >> 2;
    const int ac = (tid & 3) * 8;
    const float* xp0 = X + (size_t)(bm * BM + ar) * K_DIM + ac;
    const float* xp1 = xp0 + (size_t)64 * K_DIM;
    ushort* as0 = As + ar * BK + ac;
    ushort* as1 = as0 + 64 * BK;

    const int scol = (lane & 3) * 8;
    const ushort* Bb = B + (size_t)(bn * BN) * K_DIM;

    floatx4 acc[4][4] = {};

    for (int k0 = 0; k0 < K_DIM; k0 += BK) {
        float4 a0 = *(const float4*)(xp0 + k0);
        float4 a1 = *(const float4*)(xp0 + k0 + 4);
        float4 b0 = *(const float4*)(xp1 + k0);
        float4 b1 = *(const float4*)(xp1 + k0 + 4);
#pragma unroll
        for (int q = 0; q < 2; ++q) {
            const int chunk = wave * 2 + q;
            const int r = chunk * 16 + (lane >> 2);
            const ushort* gb = Bb + (size_t)r * K_DIM + k0 + scol;
            __builtin_amdgcn_global_load_lds(
                (const __attribute__((address_space(1))) void*)gb,
                (__attribute__((address_space(3))) void*)(Bs + chunk * 512),
                16, 0, 0);
        }
        uint4 w0, w1;
        w0.x = pk_bf_trunc(a0.x, a0.y);
        w0.y = pk_bf_trunc(a0.z, a0.w);
        w0.z = pk_bf_trunc(a1.x, a1.y);
        w0.w = pk_bf_trunc(a1.z, a1.w);
        w1.x = pk_bf_trunc(b0.x, b0.y);
        w1.y = pk_bf_trunc(b0.z, b0.w);
        w1.z = pk_bf_trunc(b1.x, b1.y);
        w1.w = pk_bf_trunc(b1.z, b1.w);
        *(uint4*)as0 = w0;
        *(uint4*)as1 = w1;

        __syncthreads();

        bf16x8 af[4], bfr[4];
        const int frow = lane & 15;
        const int fcol = (lane >> 4) * 8;
#pragma unroll
        for (int i = 0; i < 4; ++i) {
            af[i]  = *(const bf16x8*)(As + (wm * 64 + i * 16 + frow) * BK + fcol);
            bfr[i] = *(const bf16x8*)(Bs + (wn * 64 + i * 16 + frow) * BK + fcol);
        }
#pragma unroll
        for (int i = 0; i < 4; ++i)
#pragma unroll
            for (int j = 0; j < 4; ++j)
                acc[i][j] = __builtin_amdgcn_mfma_f32_16x16x32_bf16(
                    af[i], bfr[j], acc[i][j], 0, 0, 0);
        __syncthreads();
    }

    const int crow0 = bm * BM + wm * 64;
    const int ccol0 = bn * BN + wn * 64;
    const int rl = lane >> 4;
    const int cl = lane & 15;
#pragma unroll
    for (int j = 0; j < 4; ++j) {
        const int col = ccol0 + j * 16 + cl;
        const float bv = bias[col];
#pragma unroll
        for (int i = 0; i < 4; ++i) {
            const int row = crow0 + i * 16 + rl * 4;
            float* cp = C + (size_t)row * N_DIM + col;
#pragma unroll
            for (int r = 0; r < 4; ++r)
                cp[(size_t)r * N_DIM] = acc[i][j][r] + bv;
        }
    }
}

// ---------------------------------------------------------------------------
extern "C" void kernel_launch(void* const* d_in, const int* in_sizes, int n_in,
                              void* d_out, int out_size, void* d_ws, size_t ws_size,
                              hipStream_t stream) {
    const float* x      = (const float*)d_in[0];
    const int*   pw     = (const int*)d_in[1];
    const float* scales = (const float*)d_in[2];
    const float* zps    = (const float*)d_in[3];
    const float* bias   = (const float*)d_in[4];
    float* out = (float*)d_out;

    ushort* wb = (ushort*)d_ws;                        // 33.5 MB

    {
        int np4 = (N_DIM * K_DIM / 2) / 4;
        dequant_w_kernel<<<np4 / 256, 256, 0, stream>>>(
            (const int4*)pw, scales, zps, (uint4*)wb, np4);
    }

    const size_t need_full  = ((size_t)N_DIM * K_DIM + (size_t)M_DIM * K_DIM) * 2;
    const size_t need_chunk = ((size_t)N_DIM * K_DIM + (size_t)CHUNK_M * K_DIM) * 2;

    if (ws_size >= need_full) {
        // full path: convert all of x once, single GEMM over M=8192
        ushort* xb = wb + (size_t)N_DIM * K_DIM;       // 67.1 MB
        int n8 = (M_DIM * K_DIM) / 8;
        convert_x_kernel<<<n8 / 256, 256, 0, stream>>>(
            (const float4*)x, (uint4*)xb, n8);
        int nblk = (M_DIM / TBM) * (N_DIM / TBN);      // 32*16 = 512
        gemm_bf16_256<<<nblk, 512, 0, stream>>>(xb, wb, bias, out);
    } else if (ws_size >= need_chunk) {
        // chunked path
        ushort* xb = wb + (size_t)N_DIM * K_DIM;
        for (int c = 0; c < M_DIM / CHUNK_M; ++c) {
            const float* xc = x + (size_t)c * CHUNK_M * K_DIM;
            float* oc = out + (size_t)c * CHUNK_M * N_DIM;
            int n8 = (CHUNK_M * K_DIM) / 8;
            convert_x_kernel<<<n8 / 256, 256, 0, stream>>>(
                (const float4*)xc, (uint4*)xb, n8);
            int nblk = (CHUNK_M / TBM) * (N_DIM / TBN);
            gemm_bf16_256<<<nblk, 512, 0, stream>>>(xb, wb, bias, oc);
        }
    } else {
        // fallback: fused conversion
        dim3 grid(N_DIM / BN, M_DIM / BM);
        gemm_fused_kernel<<<grid, 256, 0, stream>>>(x, wb, bias, out);
    }
}

// Round 11
// 466.257 us; speedup vs baseline: 1.3163x; 1.0206x over previous
//
#include <hip/hip_runtime.h>
#include <cstdint>
#include <cstddef>

#define M_DIM 8192
#define N_DIM 4096
#define K_DIM 4096
#define CHUNK_M 4096   // chunked fallback if ws can't hold full converted x

typedef __attribute__((ext_vector_type(8))) short bf16x8;
typedef __attribute__((ext_vector_type(4))) float floatx4;

__device__ __forceinline__ ushort f2bf_rne(float f) {
    union { float f; uint32_t u; } a;
    a.f = f;
    uint32_t u = a.u;
    uint32_t r = (u + 0x7fffu + ((u >> 16) & 1u)) >> 16;
    return (ushort)r;
}

__device__ __forceinline__ uint32_t pk_bf_trunc(float f0, float f1) {
    return __builtin_amdgcn_perm(__float_as_uint(f1), __float_as_uint(f0),
                                 0x07060302u);
}

// ---------------------------------------------------------------------------
// Kernel 1: packed int4 (one signed byte per int32) -> dequant -> bf16 (RNE)
// ---------------------------------------------------------------------------
__global__ void dequant_w_kernel(const int4* __restrict__ pw,
                                 const float* __restrict__ scales,
                                 const float* __restrict__ zps,
                                 uint4* __restrict__ wb, int np4) {
    int p4 = blockIdx.x * blockDim.x + threadIdx.x;
    if (p4 >= np4) return;
    int p = p4 * 4;
    int g = p >> 18;
    float s = scales[g];
    float b = -zps[g] * s;
    int4 v = pw[p4];
    int vv[4] = { v.x, v.y, v.z, v.w };
    ushort o[8];
#pragma unroll
    for (int j = 0; j < 4; ++j) {
        int lo = ((int)((uint32_t)vv[j] << 28)) >> 28;
        int hi = ((int)((uint32_t)vv[j] << 24)) >> 28;
        o[2 * j]     = f2bf_rne(fmaf((float)lo, s, b));
        o[2 * j + 1] = f2bf_rne(fmaf((float)hi, s, b));
    }
    uint4 st;
    st.x = (uint32_t)o[0] | ((uint32_t)o[1] << 16);
    st.y = (uint32_t)o[2] | ((uint32_t)o[3] << 16);
    st.z = (uint32_t)o[4] | ((uint32_t)o[5] << 16);
    st.w = (uint32_t)o[6] | ((uint32_t)o[7] << 16);
    wb[p4] = st;
}

// ---------------------------------------------------------------------------
// Kernel 2: x fp32 -> bf16 (RNE)
// ---------------------------------------------------------------------------
__global__ void convert_x_kernel(const float4* __restrict__ x4,
                                 ushort4* __restrict__ out4, int n4) {
    int i = blockIdx.x * blockDim.x + threadIdx.x;
    if (i >= n4) return;
    float4 v = x4[i];
    ushort4 o;
    o.x = f2bf_rne(v.x);
    o.y = f2bf_rne(v.y);
    o.z = f2bf_rne(v.z);
    o.w = f2bf_rne(v.w);
    out4[i] = o;
}

// ---------------------------------------------------------------------------
// Kernel 3a: 256x256 pipelined bf16 GEMM (R8: flat counted-vmcnt schedule +
// full next-tile register prefetch -> zero in-step LDS waits). BEST: 227us.
// A [M][K] bf16 row-major, B [N][K] bf16 row-major. C = A*B^T + bias.
// 512 threads = 8 waves (2M x 4N), per-wave 128x64 output, acc[8][4].
//
// Step t computes ALL 32 MFMA of tile t from regs loaded in step t-1, and
// issues the 12 ds_reads for tile t+1's frags (3 groups of 4, interleaved
// between MFMA clusters). NO lgkmcnt in-step: reads have a full step
// (~2000 cyc) to drain under the MFMAs; compiler's auto-wait at next-step
// first-use finds them retired. Only syncs per step: vmcnt(4) + s_barrier.
//
// Invariants (ring of 4 slots):
//   stage(t+3) issued in step t into slot (t+3)&3 = slot of t-1, whose
//   readers (frag reads for t-1, issued step t-2) completed before their
//   use in step t-1 < beta(t-1).  Reads in step t target slot (t+1)&3;
//   writes in flight target (t+2)&3, (t+3)&3 - distinct mod 4.
//   vmcnt(4) at end of step t certifies stage(t+2) landed (4 loads of
//   t+3 may fly); BODY(t+1)'s reads of tile t+2 are therefore safe.
//
// T2 swizzle (BK=32, rows = 4 x 16B slots): slot' = slot ^ ((row>>1)&3),
// applied as inverse-swizzled GLOBAL source (LDS dest stays linear for
// global_load_lds) + swizzled fragment-read address (per-lane constant).
//
// NOTE (R7/R9 negative results): replacing either operand's DMA+LDS path
// with per-lane VMEM (fused fp32 A, direct-reg B) regresses ~2x — gather
// transaction-splitting + same-step vmcnt latency lands on the critical
// path. Keep both operands on global_load_lds.
// ---------------------------------------------------------------------------
#define TBM 256
#define TBN 256
#define TBK 32
#define NT  (K_DIM / TBK)        // 128 K-steps
#define A_E 8192                 // elements of A per slot (256*32)
#define SLOT_E 16384             // elements per ring slot (A + B)

__global__ __launch_bounds__(512, 2)
void gemm_bf16_256(const ushort* __restrict__ A,
                   const ushort* __restrict__ B,
                   const float* __restrict__ bias,
                   float* __restrict__ C) {
    __shared__ ushort lds[4 * SLOT_E];   // 128 KiB -> 1 block/CU, 8 waves

    const int tid  = threadIdx.x;
    const int lane = tid & 63;
    const int wave = tid >> 6;
    const int wm   = wave >> 2;          // 0..1
    const int wn   = wave & 3;           // 0..3

    // T1: XCD-chunked bijective swizzle (nwg % 8 == 0)
    const int nwg = gridDim.x;
    const int cpx = nwg >> 3;
    const int bid = blockIdx.x;
    const int swz = (bid & 7) * cpx + (bid >> 3);
    const int bn  = swz & (N_DIM / TBN - 1);
    const int bm  = swz / (N_DIM / TBN);

    const ushort* Ab = A + (size_t)(bm * TBM) * K_DIM;
    const ushort* Bb = B + (size_t)(bn * TBN) * K_DIM;

    // staging: thread tid covers LDS offset tid*16B of an 8KB part
    // -> part row tid>>2 (0..127); T2: fetch INVERSE-swizzled global k-chunk
    const int srow = tid >> 2;
    const int scol = (((tid & 3) ^ ((tid >> 3) & 3)) * 8);
    const ushort* gA0 = Ab + (size_t)srow * K_DIM + scol;
    const ushort* gA1 = gA0 + (size_t)128 * K_DIM;
    const ushort* gB0 = Bb + (size_t)srow * K_DIM + scol;
    const ushort* gB1 = gB0 + (size_t)128 * K_DIM;
    const int wdst = wave * 512;         // this wave's 1KB within a part

    // MFMA fragment addressing: T2 swizzled slot, constant per lane
    const int frow = lane & 15;
    const int fcol = (((lane >> 4) ^ ((frow >> 1) & 3)) * 8);
    const int aoff = (wm * 128 + frow) * TBK + fcol;          // within A region
    const int boff = A_E + (wn * 64 + frow) * TBK + fcol;     // within B region

    floatx4 acc[8][4] = {};

#define STAGE_A(tt)                                                           \
    {                                                                          \
        const int k0s = ((tt) & (NT - 1)) * TBK;                               \
        ushort* d = lds + ((tt) & 3) * SLOT_E + wdst;                          \
        __builtin_amdgcn_global_load_lds(                                      \
            (const __attribute__((address_space(1))) void*)(gA0 + k0s),        \
            (__attribute__((address_space(3))) void*)d, 16, 0, 0);             \
        __builtin_amdgcn_global_load_lds(                                      \
            (const __attribute__((address_space(1))) void*)(gA1 + k0s),        \
            (__attribute__((address_space(3))) void*)(d + 4096), 16, 0, 0);    \
    }
#define STAGE_B(tt)                                                           \
    {                                                                          \
        const int k0s = ((tt) & (NT - 1)) * TBK;                               \
        ushort* d = lds + ((tt) & 3) * SLOT_E + A_E + wdst;                    \
        __builtin_amdgcn_global_load_lds(                                      \
            (const __attribute__((address_space(1))) void*)(gB0 + k0s),        \
            (__attribute__((address_space(3))) void*)d, 16, 0, 0);             \
        __builtin_amdgcn_global_load_lds(                                      \
            (const __attribute__((address_space(1))) void*)(gB1 + k0s),        \
            (__attribute__((address_space(3))) void*)(d + 4096), 16, 0, 0);    \
    }

// one K-step: consume tile T's frags (afc[8], bfc[4], loaded last step);
// prefetch tile T+1's frags into afn[8]/bfn[4]; stage tile T+3.
#define BODY(T, afc, bfc, afn, bfn)                                           \
    {                                                                          \
        const ushort* bnxt = lds + (((T) + 1) & 3) * SLOT_E;                   \
        /* G1: afn[0..3] + stage A(t+3) */                                     \
        _Pragma("unroll")                                                      \
        for (int i = 0; i < 4; ++i)                                            \
            afn[i] = *(const bf16x8*)(bnxt + aoff + i * 512);                  \
        STAGE_A((T) + 3)                                                       \
        __builtin_amdgcn_sched_barrier(0);                                     \
        __builtin_amdgcn_s_setprio(1);                                         \
        _Pragma("unroll")                                                      \
        for (int i = 0; i < 2; ++i)                                            \
            _Pragma("unroll")                                                  \
            for (int j = 0; j < 4; ++j)                                        \
                acc[i][j] = __builtin_amdgcn_mfma_f32_16x16x32_bf16(           \
                    afc[i], bfc[j], acc[i][j], 0, 0, 0);                       \
        __builtin_amdgcn_s_setprio(0);                                         \
        __builtin_amdgcn_sched_barrier(0);                                     \
        /* G2: bfn[0..3] + stage B(t+3) */                                     \
        _Pragma("unroll")                                                      \
        for (int j = 0; j < 4; ++j)                                            \
            bfn[j] = *(const bf16x8*)(bnxt + boff + j * 512);                  \
        STAGE_B((T) + 3)                                                       \
        __builtin_amdgcn_sched_barrier(0);                                     \
        __builtin_amdgcn_s_setprio(1);                                         \
        _Pragma("unroll")                                                      \
        for (int i = 2; i < 4; ++i)                                            \
            _Pragma("unroll")                                                  \
            for (int j = 0; j < 4; ++j)                                        \
                acc[i][j] = __builtin_amdgcn_mfma_f32_16x16x32_bf16(           \
                    afc[i], bfc[j], acc[i][j], 0, 0, 0);                       \
        __builtin_amdgcn_s_setprio(0);                                         \
        __builtin_amdgcn_sched_barrier(0);                                     \
        /* G3: afn[4..7] */                                                    \
        _Pragma("unroll")                                                      \
        for (int i = 4; i < 8; ++i)                                            \
            afn[i] = *(const bf16x8*)(bnxt + aoff + i * 512);                  \
        __builtin_amdgcn_sched_barrier(0);                                     \
        __builtin_amdgcn_s_setprio(1);                                         \
        _Pragma("unroll")                                                      \
        for (int i = 4; i < 8; ++i)                                            \
            _Pragma("unroll")                                                  \
            for (int j = 0; j < 4; ++j)                                        \
                acc[i][j] = __builtin_amdgcn_mfma_f32_16x16x32_bf16(           \
                    afc[i], bfc[j], acc[i][j], 0, 0, 0);                       \
        __builtin_amdgcn_s_setprio(0);                                         \
        /* certify stage(t+2) landed (t+3's 4 loads may fly) */                \
        asm volatile("s_waitcnt vmcnt(4)" ::: "memory");                       \
        __builtin_amdgcn_s_barrier();                                          \
        __builtin_amdgcn_sched_barrier(0);                                     \
    }

    // prologue: tiles 0,1,2 in flight; vmcnt(4) -> tiles 0,1 landed (2 flying)
    STAGE_A(0) STAGE_B(0)
    STAGE_A(1) STAGE_B(1)
    STAGE_A(2) STAGE_B(2)
    asm volatile("s_waitcnt vmcnt(4)" ::: "memory");
    __builtin_amdgcn_s_barrier();
    __builtin_amdgcn_sched_barrier(0);

    // initial fragment set: tile 0 (slot 0). Tile 1 is also certified landed,
    // so BODY(0)'s prefetch of tile 1 is safe.
    bf16x8 af0[8], bf0[4], af1[8], bf1[4];
#pragma unroll
    for (int j = 0; j < 4; ++j)
        bf0[j] = *(const bf16x8*)(lds + boff + j * 512);
#pragma unroll
    for (int i = 0; i < 8; ++i)
        af0[i] = *(const bf16x8*)(lds + aoff + i * 512);

    for (int t = 0; t < NT; t += 2) {
        BODY(t,     af0, bf0, af1, bf1)
        BODY(t + 1, af1, bf1, af0, bf0)
    }
#undef BODY
#undef STAGE_A
#undef STAGE_B

    // epilogue: C = acc + bias
    const int crow0 = bm * TBM + wm * 128;
    const int ccol0 = bn * TBN + wn * 64;
    const int rl = lane >> 4;
    const int cl = lane & 15;
#pragma unroll
    for (int j = 0; j < 4; ++j) {
        const int col = ccol0 + j * 16 + cl;
        const float bv = bias[col];
#pragma unroll
        for (int i = 0; i < 8; ++i) {
            const int row = crow0 + i * 16 + rl * 4;
            float* cp = C + (size_t)row * N_DIM + col;
#pragma unroll
            for (int r = 0; r < 4; ++r)
                cp[(size_t)r * N_DIM] = acc[i][j][r] + bv;
        }
    }
}

// ---------------------------------------------------------------------------
// Kernel 3b (fallback if ws too small): fused fp32-A GEMM, 128x128 tile.
// ---------------------------------------------------------------------------
#define BM 128
#define BN 128
#define BK 32

__global__ void gemm_fused_kernel(const float* __restrict__ X,
                                  const ushort* __restrict__ B,
                                  const float* __restrict__ bias,
                                  float* __restrict__ C) {
    __shared__ ushort As[BM * BK];
    __shared__ ushort Bs[BN * BK];

    const int tid  = threadIdx.x;
    const int lane = tid & 63;
    const int wave = tid >> 6;
    const int wm   = wave >> 1;
    const int wn   = wave & 1;
    const int bm   = blockIdx.y;
    const int bn   = blockIdx.x;

    const int ar = tid >> 2;
    const int ac = (tid & 3) * 8;
    const float* xp0 = X + (size_t)(bm * BM + ar) * K_DIM + ac;
    const float* xp1 = xp0 + (size_t)64 * K_DIM;
    ushort* as0 = As + ar * BK + ac;
    ushort* as1 = as0 + 64 * BK;

    const int scol = (lane & 3) * 8;
    const ushort* Bb = B + (size_t)(bn * BN) * K_DIM;

    floatx4 acc[4][4] = {};

    for (int k0 = 0; k0 < K_DIM; k0 += BK) {
        float4 a0 = *(const float4*)(xp0 + k0);
        float4 a1 = *(const float4*)(xp0 + k0 + 4);
        float4 b0 = *(const float4*)(xp1 + k0);
        float4 b1 = *(const float4*)(xp1 + k0 + 4);
#pragma unroll
        for (int q = 0; q < 2; ++q) {
            const int chunk = wave * 2 + q;
            const int r = chunk * 16 + (lane >> 2);
            const ushort* gb = Bb + (size_t)r * K_DIM + k0 + scol;
            __builtin_amdgcn_global_load_lds(
                (const __attribute__((address_space(1))) void*)gb,
                (__attribute__((address_space(3))) void*)(Bs + chunk * 512),
                16, 0, 0);
        }
        uint4 w0, w1;
        w0.x = pk_bf_trunc(a0.x, a0.y);
        w0.y = pk_bf_trunc(a0.z, a0.w);
        w0.z = pk_bf_trunc(a1.x, a1.y);
        w0.w = pk_bf_trunc(a1.z, a1.w);
        w1.x = pk_bf_trunc(b0.x, b0.y);
        w1.y = pk_bf_trunc(b0.z, b0.w);
        w1.z = pk_bf_trunc(b1.x, b1.y);
        w1.w = pk_bf_trunc(b1.z, b1.w);
        *(uint4*)as0 = w0;
        *(uint4*)as1 = w1;

        __syncthreads();

        bf16x8 af[4], bfr[4];
        const int frow = lane & 15;
        const int fcol = (lane >> 4) * 8;
#pragma unroll
        for (int i = 0; i < 4; ++i) {
            af[i]  = *(const bf16x8*)(As + (wm * 64 + i * 16 + frow) * BK + fcol);
            bfr[i] = *(const bf16x8*)(Bs + (wn * 64 + i * 16 + frow) * BK + fcol);
        }
#pragma unroll
        for (int i = 0; i < 4; ++i)
#pragma unroll
            for (int j = 0; j < 4; ++j)
                acc[i][j] = __builtin_amdgcn_mfma_f32_16x16x32_bf16(
                    af[i], bfr[j], acc[i][j], 0, 0, 0);
        __syncthreads();
    }

    const int crow0 = bm * BM + wm * 64;
    const int ccol0 = bn * BN + wn * 64;
    const int rl = lane >> 4;
    const int cl = lane & 15;
#pragma unroll
    for (int j = 0; j < 4; ++j) {
        const int col = ccol0 + j * 16 + cl;
        const float bv = bias[col];
#pragma unroll
        for (int i = 0; i < 4; ++i) {
            const int row = crow0 + i * 16 + rl * 4;
            float* cp = C + (size_t)row * N_DIM + col;
#pragma unroll
            for (int r = 0; r < 4; ++r)
                cp[(size_t)r * N_DIM] = acc[i][j][r] + bv;
        }
    }
}

// ---------------------------------------------------------------------------
extern "C" void kernel_launch(void* const* d_in, const int* in_sizes, int n_in,
                              void* d_out, int out_size, void* d_ws, size_t ws_size,
                              hipStream_t stream) {
    const float* x      = (const float*)d_in[0];
    const int*   pw     = (const int*)d_in[1];
    const float* scales = (const float*)d_in[2];
    const float* zps    = (const float*)d_in[3];
    const float* bias   = (const float*)d_in[4];
    float* out = (float*)d_out;

    ushort* wb = (ushort*)d_ws;                        // 33.5 MB

    {
        int np4 = (N_DIM * K_DIM / 2) / 4;
        dequant_w_kernel<<<np4 / 256, 256, 0, stream>>>(
            (const int4*)pw, scales, zps, (uint4*)wb, np4);
    }

    const size_t need_full  = ((size_t)N_DIM * K_DIM + (size_t)M_DIM * K_DIM) * 2;
    const size_t need_chunk = ((size_t)N_DIM * K_DIM + (size_t)CHUNK_M * K_DIM) * 2;

    if (ws_size >= need_full) {
        // full path: convert all of x once, single GEMM over M=8192
        ushort* xb = wb + (size_t)N_DIM * K_DIM;       // 67.1 MB
        int n4 = (M_DIM * K_DIM) / 4;
        convert_x_kernel<<<n4 / 256, 256, 0, stream>>>(
            (const float4*)x, (ushort4*)xb, n4);
        int nblk = (M_DIM / TBM) * (N_DIM / TBN);      // 32*16 = 512
        gemm_bf16_256<<<nblk, 512, 0, stream>>>(xb, wb, bias, out);
    } else if (ws_size >= need_chunk) {
        // chunked path
        ushort* xb = wb + (size_t)N_DIM * K_DIM;
        for (int c = 0; c < M_DIM / CHUNK_M; ++c) {
            const float* xc = x + (size_t)c * CHUNK_M * K_DIM;
            float* oc = out + (size_t)c * CHUNK_M * N_DIM;
            int n4 = (CHUNK_M * K_DIM) / 4;
            convert_x_kernel<<<n4 / 256, 256, 0, stream>>>(
                (const float4*)xc, (ushort4*)xb, n4);
            int nblk = (CHUNK_M / TBM) * (N_DIM / TBN);
            gemm_bf16_256<<<nblk, 512, 0, stream>>>(xb, wb, bias, oc);
        }
    } else {
        // fallback: fused conversion
        dim3 grid(N_DIM / BN, M_DIM / BM);
        gemm_fused_kernel<<<grid, 256, 0, stream>>>(x, wb, bias, out);
    }
}